// Round 1
// baseline (83.773 us; speedup 1.0000x reference)
//
#include <hip/hip_runtime.h>

// Diversity5: out = mean_b( SCALE * sum_{i<j} corr(v_i[b], v_j[b]) )
// where v_m = normalize(center(softmax(outputs_m / T))).
// Identities used:
//   mean_c(softmax) == 1/C  (softmax sums to 1)
//   sum_{i<j} v_i.v_j == (||sum_m v_m||^2 - M) / 2   (unit-norm v_m)
// => single streaming pass, one wave per batch row, no LDS in the hot kernel.

#define CDIM   1000
#define C4DIM  250              // CDIM / 4 float4s per row
#define NMODEL 5
#define T_INV  (1.0f / 20.0f)
#define INV_C  (1.0f / 1000.0f)
#define SCALEF 0.3f

__device__ __forceinline__ float wave_sum_f32(float v) {
    #pragma unroll
    for (int off = 32; off >= 1; off >>= 1)
        v += __shfl_xor(v, off);
    return v;
}

__device__ __forceinline__ float wave_max_f32(float v) {
    #pragma unroll
    for (int off = 32; off >= 1; off >>= 1)
        v = fmaxf(v, __shfl_xor(v, off));
    return v;
}

__global__ __launch_bounds__(256) void diversity_rows(
    const float* __restrict__ o1, const float* __restrict__ o2,
    const float* __restrict__ o3, const float* __restrict__ o4,
    const float* __restrict__ o5, float* __restrict__ ws, int B)
{
    const int lane = threadIdx.x & 63;
    const int wid  = threadIdx.x >> 6;
    const int b    = blockIdx.x * 4 + wid;
    if (b >= B) return;

    // Lane owns float4 slots {lane, lane+64, lane+128, lane+192}; slot 3 is
    // partial (active iff lane+192 < 250, i.e. lane < 58).
    const bool act3 = (lane + 192) < C4DIM;

    float s[16];
    #pragma unroll
    for (int i = 0; i < 16; ++i) s[i] = 0.0f;

    #pragma unroll
    for (int m = 0; m < NMODEL; ++m) {
        const float* rowp;
        if      (m == 0) rowp = o1;
        else if (m == 1) rowp = o2;
        else if (m == 2) rowp = o3;
        else if (m == 3) rowp = o4;
        else             rowp = o5;
        const float4* row4 = reinterpret_cast<const float4*>(rowp + (size_t)b * CDIM);

        // ---- load 16 elements (4 aligned float4), inactive slot -> -1e30 ----
        float xv[16];
        #pragma unroll
        for (int k = 0; k < 4; ++k) {
            float4 t;
            if (k < 3 || act3) t = row4[lane + 64 * k];
            else               t = make_float4(-1e30f, -1e30f, -1e30f, -1e30f);
            xv[4 * k + 0] = t.x; xv[4 * k + 1] = t.y;
            xv[4 * k + 2] = t.z; xv[4 * k + 3] = t.w;
        }

        // ---- row max (of raw logits; softmax arg is x/T) ----
        float lmax = -1e30f;
        #pragma unroll
        for (int i = 0; i < 16; ++i) lmax = fmaxf(lmax, xv[i]);
        lmax = wave_max_f32(lmax);

        // ---- e = exp((x - max)/T); inactive -> exp(very negative) = 0 ----
        float ev[16];
        float lsum = 0.0f;
        #pragma unroll
        for (int i = 0; i < 16; ++i) {
            float e = expf((xv[i] - lmax) * T_INV);
            ev[i] = e;
            lsum += e;
        }
        const float S  = wave_sum_f32(lsum);
        const float rS = 1.0f / S;

        // ---- v = p - 1/C; accumulate ||v||^2 (centered: no cancellation) ----
        float vv[16];
        float lss = 0.0f;
        #pragma unroll
        for (int i = 0; i < 16; ++i) {
            float v = ev[i] * rS - INV_C;
            if (i >= 12 && !act3) v = 0.0f;   // mask padded elements
            vv[i] = v;
            lss += v * v;
        }
        const float n2 = wave_sum_f32(lss);
        const float rn = 1.0f / sqrtf(n2);

        // ---- s += v / ||v|| ----
        #pragma unroll
        for (int i = 0; i < 16; ++i) s[i] += vv[i] * rn;
    }

    // ---- d[b] = (||s||^2 - M) / 2 ; write SCALE * d ----
    float lss = 0.0f;
    #pragma unroll
    for (int i = 0; i < 16; ++i) lss += s[i] * s[i];
    const float ss = wave_sum_f32(lss);
    if (lane == 0)
        ws[b] = SCALEF * 0.5f * (ss - (float)NMODEL);
}

// Deterministic fixed-order reduction of B partials -> mean, in double.
__global__ __launch_bounds__(256) void final_reduce(
    const float* __restrict__ ws, float* __restrict__ out, int B)
{
    __shared__ double sm[256];
    double acc = 0.0;
    for (int i = threadIdx.x; i < B; i += 256)
        acc += (double)ws[i];
    sm[threadIdx.x] = acc;
    __syncthreads();
    #pragma unroll
    for (int s = 128; s > 0; s >>= 1) {
        if (threadIdx.x < s) sm[threadIdx.x] += sm[threadIdx.x + s];
        __syncthreads();
    }
    if (threadIdx.x == 0)
        out[0] = (float)(sm[0] / (double)B);
}

extern "C" void kernel_launch(void* const* d_in, const int* in_sizes, int n_in,
                              void* d_out, int out_size, void* d_ws, size_t ws_size,
                              hipStream_t stream)
{
    const float* o1 = (const float*)d_in[0];
    const float* o2 = (const float*)d_in[1];
    const float* o3 = (const float*)d_in[2];
    const float* o4 = (const float*)d_in[3];
    const float* o5 = (const float*)d_in[4];
    // d_in[5] (targets) is unused by the reference.

    float* ws  = (float*)d_ws;
    float* out = (float*)d_out;

    const int B = in_sizes[0] / CDIM;   // 16384

    diversity_rows<<<(B + 3) / 4, 256, 0, stream>>>(o1, o2, o3, o4, o5, ws, B);
    final_reduce<<<1, 256, 0, stream>>>(ws, out, B);
}

// Round 3
// 65.216 us; speedup vs baseline: 1.2845x; 1.2845x over previous
//
#include <hip/hip_runtime.h>

// Diversity5: out = mean_b( SCALE * sum_{i<j} corr(v_i[b], v_j[b]) )
// v_m = normalize(center(softmax(outputs_m / T))).
// Identities:
//   mean_c(softmax) == 1/C                      (softmax sums to 1)
//   sum_{i<j} v_i.v_j == (||sum_m v_m||^2-M)/2  (unit-norm v_m)
// R1 restructure: all 20 float4 loads hoisted up front (pay HBM latency once),
// max-subtraction dropped (logits/T in +-0.3 -> exp safe), __expf (2 instrs),
// and the 5 models' butterfly reductions interleaved for 5x ILP on the
// ds_bpermute latency chains. Centered ||v||^2 kept (cancellation-safe).

#define CDIM   1000
#define C4DIM  250
#define NMODEL 5
#define T_INV  (1.0f / 20.0f)
#define INV_C  (1.0f / 1000.0f)
#define SCALEF 0.3f

__device__ __forceinline__ float wave_sum_f32(float v) {
    #pragma unroll
    for (int off = 32; off >= 1; off >>= 1)
        v += __shfl_xor(v, off);
    return v;
}

__global__ __launch_bounds__(256) void diversity_rows(
    const float* __restrict__ o1, const float* __restrict__ o2,
    const float* __restrict__ o3, const float* __restrict__ o4,
    const float* __restrict__ o5, float* __restrict__ ws, int B)
{
    const int lane = threadIdx.x & 63;
    const int wid  = threadIdx.x >> 6;
    const int b    = blockIdx.x * 4 + wid;
    if (b >= B) return;

    // Lane owns float4 slots {lane, lane+64, lane+128, lane+192}; slot 3
    // active iff lane < 58 (250 float4s per row).
    const bool act3 = lane < (C4DIM - 192);

    const size_t roff = (size_t)b * CDIM;
    const float4* r4[NMODEL] = {
        reinterpret_cast<const float4*>(o1 + roff),
        reinterpret_cast<const float4*>(o2 + roff),
        reinterpret_cast<const float4*>(o3 + roff),
        reinterpret_cast<const float4*>(o4 + roff),
        reinterpret_cast<const float4*>(o5 + roff)};

    // ---------- phase 0: issue ALL 20 loads ----------
    float e[NMODEL][16];
    #pragma unroll
    for (int m = 0; m < NMODEL; ++m) {
        #pragma unroll
        for (int k = 0; k < 4; ++k) {
            float4 t = make_float4(0.0f, 0.0f, 0.0f, 0.0f);
            if (k < 3 || act3) t = r4[m][lane + 64 * k];
            e[m][4 * k + 0] = t.x; e[m][4 * k + 1] = t.y;
            e[m][4 * k + 2] = t.z; e[m][4 * k + 3] = t.w;
        }
    }

    // ---------- phase 1: exp + local sums (no max: |x/T| <= ~0.3) ----------
    float lsum[NMODEL];
    #pragma unroll
    for (int m = 0; m < NMODEL; ++m) {
        float a = 0.0f;
        #pragma unroll
        for (int i = 0; i < 16; ++i) {
            float ev = __expf(e[m][i] * T_INV);
            if (i >= 12 && !act3) ev = 0.0f;   // mask padded tail
            e[m][i] = ev;
            a += ev;
        }
        lsum[m] = a;
    }
    // 5 interleaved butterfly chains (independent -> latency hidden)
    #pragma unroll
    for (int off = 32; off >= 1; off >>= 1) {
        #pragma unroll
        for (int m = 0; m < NMODEL; ++m)
            lsum[m] += __shfl_xor(lsum[m], off);
    }
    float rS[NMODEL];
    #pragma unroll
    for (int m = 0; m < NMODEL; ++m) rS[m] = 1.0f / lsum[m];

    // ---------- phase 2: center (exact mean 1/C) + ||v||^2 ----------
    float lss[NMODEL];
    #pragma unroll
    for (int m = 0; m < NMODEL; ++m) {
        float a = 0.0f;
        #pragma unroll
        for (int i = 0; i < 16; ++i) {
            float v = e[m][i] * rS[m] - INV_C;
            if (i >= 12 && !act3) v = 0.0f;
            e[m][i] = v;
            a += v * v;
        }
        lss[m] = a;
    }
    #pragma unroll
    for (int off = 32; off >= 1; off >>= 1) {
        #pragma unroll
        for (int m = 0; m < NMODEL; ++m)
            lss[m] += __shfl_xor(lss[m], off);
    }
    float rn[NMODEL];
    #pragma unroll
    for (int m = 0; m < NMODEL; ++m) rn[m] = 1.0f / sqrtf(lss[m]);

    // ---------- phase 3: s = sum_m v_m/||v_m||; d = (||s||^2 - M)/2 ----------
    float ssl = 0.0f;
    #pragma unroll
    for (int i = 0; i < 16; ++i) {
        float si = e[0][i] * rn[0];
        #pragma unroll
        for (int m = 1; m < NMODEL; ++m) si += e[m][i] * rn[m];
        ssl += si * si;
    }
    const float ss = wave_sum_f32(ssl);
    if (lane == 0)
        ws[b] = SCALEF * 0.5f * (ss - (float)NMODEL);
}

// Deterministic fixed-order reduction of B partials -> mean, in double.
__global__ __launch_bounds__(1024) void final_reduce(
    const float* __restrict__ ws, float* __restrict__ out, int B)
{
    __shared__ double sm[1024];
    double acc = 0.0;
    for (int i = threadIdx.x; i < B; i += 1024)
        acc += (double)ws[i];
    sm[threadIdx.x] = acc;
    __syncthreads();
    #pragma unroll
    for (int s = 512; s > 0; s >>= 1) {
        if (threadIdx.x < s) sm[threadIdx.x] += sm[threadIdx.x + s];
        __syncthreads();
    }
    if (threadIdx.x == 0)
        out[0] = (float)(sm[0] / (double)B);
}

extern "C" void kernel_launch(void* const* d_in, const int* in_sizes, int n_in,
                              void* d_out, int out_size, void* d_ws, size_t ws_size,
                              hipStream_t stream)
{
    const float* o1 = (const float*)d_in[0];
    const float* o2 = (const float*)d_in[1];
    const float* o3 = (const float*)d_in[2];
    const float* o4 = (const float*)d_in[3];
    const float* o5 = (const float*)d_in[4];
    // d_in[5] (targets) unused by the reference.

    float* ws  = (float*)d_ws;
    float* out = (float*)d_out;

    const int B = in_sizes[0] / CDIM;   // 16384

    diversity_rows<<<(B + 3) / 4, 256, 0, stream>>>(o1, o2, o3, o4, o5, ws, B);
    final_reduce<<<1, 1024, 0, stream>>>(ws, out, B);
}